// Round 13
// baseline (978.292 us; speedup 1.0000x reference)
//
#include <hip/hip_runtime.h>
#include <hip/hip_bf16.h>
#include <math.h>

#define SEQ_LEN 8192
#define LAT 64
#define NPOS 8256          // SEQ_LEN + LAT
#define NBATCH 16
#define NHEADS 8
#define DH 64
#define DIM 512
#define NBH 128            // NBATCH*NHEADS
#define NROWS 132096       // NBATCH*NPOS = 129*1024
#define NCHUNK 4
#define NTILES 129         // NPOS/64
#define TPC 33             // tiles per chunk (4*33=132 >= 129)

typedef unsigned short u16;
typedef unsigned int   u32;
using short8 = __attribute__((ext_vector_type(8))) short;  // MFMA bf16 A/B frag
using f32x4  = __attribute__((ext_vector_type(4))) float;  // MFMA C/D frag

static __device__ __forceinline__ float bf2f(u16 u) {
  union { u32 i; float f; } v; v.i = ((u32)u) << 16; return v.f;
}
static __device__ __forceinline__ u16 f2bf(float f) {  // round-to-nearest-even (manual, known-good)
  union { float f; u32 i; } v; v.f = f;
  u32 x = v.i;
  return (u16)((x + 0x7fffu + ((x >> 16) & 1u)) >> 16);
}
static __device__ __forceinline__ void gload_lds16(const void* g, void* l) {
  __builtin_amdgcn_global_load_lds(
      (const __attribute__((address_space(1))) unsigned int*)g,
      (__attribute__((address_space(3))) unsigned int*)l, 16, 0, 0);
}

// ---------------- kernel 0: rope tables ----------------
__global__ void k_rtable(float* __restrict__ ctab, float* __restrict__ stab) {
  int idx = blockIdx.x * 256 + threadIdx.x;   // NPOS*32 total
  int pos = idx >> 5, i = idx & 31;
  float inv = (float)(1.0 / pow(10000.0, (double)(2 * i) / 64.0));
  float ang = (float)pos * inv;
  ctab[idx] = cosf(ang);
  stab[idx] = sinf(ang);
}

// ---------------- kernel 0b: cast wkv to bf16 ----------------
__global__ __launch_bounds__(256) void k_wcast(const float* __restrict__ wkv, u16* __restrict__ wbf) {
  size_t i = (size_t)blockIdx.x * 256 + threadIdx.x;   // DIM*DIM/8 iters
  const float4* src = (const float4*)wkv;
  float4 a = src[2 * i], b = src[2 * i + 1];
  uint4 o;
  o.x = (u32)f2bf(a.x) | ((u32)f2bf(a.y) << 16);
  o.y = (u32)f2bf(a.z) | ((u32)f2bf(a.w) << 16);
  o.z = (u32)f2bf(b.x) | ((u32)f2bf(b.y) << 16);
  o.w = (u32)f2bf(b.z) | ((u32)f2bf(b.w) << 16);
  ((uint4*)wbf)[i] = o;
}

// ---------------- kernel 1: q projection (latent rows only) + rope + scale ----------------
__global__ __launch_bounds__(256) void k_qproj(
    const float* __restrict__ x, const float* __restrict__ wq,
    const float* __restrict__ ctab, const float* __restrict__ stab,
    u16* __restrict__ qws) {
  __shared__ __align__(16) float xs[8 * 512];
  int t = threadIdx.x;
  int lr0 = blockIdx.x * 8;
  int batch = lr0 >> 6;
  int lat0 = lr0 & 63;
  for (int u = 0; u < 4; ++u) {
    int e = u * 256 + t;
    int row = e >> 7, c4 = e & 127;
    size_t m = (size_t)batch * NPOS + SEQ_LEN + lat0 + row;
    ((float4*)xs)[e] = ((const float4*)(x + m * DIM))[c4];
  }
  __syncthreads();
  float acc0[8], acc1[8];
#pragma unroll
  for (int r = 0; r < 8; ++r) { acc0[r] = 0.f; acc1[r] = 0.f; }
  const float4* w0 = (const float4*)(wq + (size_t)t * DIM);
  const float4* w1 = (const float4*)(wq + (size_t)(t + 256) * DIM);
  for (int kk = 0; kk < 128; ++kk) {
    float4 a = w0[kk], b = w1[kk];
#pragma unroll
    for (int r = 0; r < 8; ++r) {
      float4 xv = ((const float4*)xs)[r * 128 + kk];
      acc0[r] = fmaf(a.x, xv.x, fmaf(a.y, xv.y, fmaf(a.z, xv.z, fmaf(a.w, xv.w, acc0[r]))));
      acc1[r] = fmaf(b.x, xv.x, fmaf(b.y, xv.y, fmaf(b.z, xv.z, fmaf(b.w, xv.w, acc1[r]))));
    }
  }
  __syncthreads();
#pragma unroll
  for (int r = 0; r < 8; ++r) { xs[r * 512 + t] = acc0[r]; xs[r * 512 + t + 256] = acc1[r]; }
  __syncthreads();
  int rh = t >> 2, sub = t & 3;
  int row = rh >> 3, head = rh & 7;
  int lat = lat0 + row, pos = SEQ_LEN + lat;
  int bh = batch * 8 + head;
  u16* qd = qws + ((size_t)bh * LAT + lat) * DH;
#pragma unroll
  for (int u = 0; u < 8; ++u) {
    int i = sub * 8 + u;
    float v1 = xs[row * 512 + head * 64 + i];
    float v2 = xs[row * 512 + head * 64 + i + 32];
    float cc = ctab[pos * 32 + i], ss = stab[pos * 32 + i];
    qd[i]      = f2bf((v1 * cc - v2 * ss) * 0.125f);
    qd[i + 32] = f2bf((v2 * cc + v1 * ss) * 0.125f);
  }
}

// ---------------- kernel 2: kv GEMM, B-head resident in LDS, barrier-free m-loop ----------------
// 1032 blocks x 512 thr (8 waves). Block = (head nh, 1024-row m-chunk). Stage wkv head slice
// (64 cols x 512 K bf16 = 64KB, XOR-swizzled via pre-swizzled global src) ONCE; one barrier;
// then 4 passes x (wave = 32 rows x 64 cols) with A loaded f32-direct (2-deep reg ring, in-reg
// RNE cvt) and B via conflict-free swizzled ds_read_b128. NO barriers in the loop.
// 8 sibling blocks (8 heads, same m-chunk) share one XCD -> x HBM-read ~once, L2 serves rest.
// Epilogue: R10's refcheck-passed in-register rope + LN (shfl over c-bits).
__global__ __launch_bounds__(512, 4) void k_kvgemm(
    const float* __restrict__ x, const u16* __restrict__ wbf,
    const float* __restrict__ ctab, const float* __restrict__ stab,
    u16* __restrict__ kvws, float2* __restrict__ stats) {
  __shared__ __align__(16) u16 Bs[64 * 512];   // 64KB
  const int t = threadIdx.x;
  const int lane = t & 63, w = t >> 6;         // 8 waves
  const int c = lane & 15, g = lane >> 4;
  // block -> (nh, mchunk): bids {xcd, nh, mgroup}: nh = (bid>>3)&7 varies within same XCD slot
  int bid = blockIdx.x;
  int nh, mchunk;
  if (bid < 1024) { nh = (bid >> 3) & 7; mchunk = (bid >> 6) * 8 + (bid & 7); }
  else            { nh = bid - 1024;     mchunk = 128; }
  const int n0 = nh * 64;

  {  // stage B head-slice, pre-swizzled source -> linear LDS (rule-21 pair)
    int colt = t >> 6;
    int kb = (t & 63) * 16;
#pragma unroll
    for (int u = 0; u < 8; ++u) {
      int col = u * 8 + colt;
      int kbs = kb ^ ((col & 7) << 4);
      gload_lds16(wbf + (size_t)(n0 + col) * DIM + (kbs >> 1),
                  (char*)Bs + u * 8192 + t * 16);
    }
  }
  __syncthreads();                              // only block-wide sync in this kernel

  const size_t mbase = (size_t)mchunk * 1024;
#pragma unroll 1
  for (int pass = 0; pass < 4; ++pass) {
    const int m0w = (int)mbase + pass * 256 + w * 32;
    const float* ax = x + (size_t)(m0w + c) * DIM + g * 8;

    f32x4 acc[2][4];
#pragma unroll
    for (int mt = 0; mt < 2; ++mt)
#pragma unroll
      for (int nt = 0; nt < 4; ++nt) acc[mt][nt] = (f32x4){0.f, 0.f, 0.f, 0.f};

    float4 aN[2][2][2];                         // ring x mt x half
#pragma unroll
    for (int ring = 0; ring < 2; ++ring)
#pragma unroll
      for (int mt = 0; mt < 2; ++mt) {
        const float* p = ax + (size_t)mt * 16 * DIM + ring * 32;
        aN[ring][mt][0] = *(const float4*)p;
        aN[ring][mt][1] = *(const float4*)(p + 4);
      }

#pragma unroll
    for (int ks = 0; ks < 16; ++ks) {
      const int ring = ks & 1;
      short8 am[2];
#pragma unroll
      for (int mt = 0; mt < 2; ++mt) {
        float4 lo = aN[ring][mt][0], hi = aN[ring][mt][1];
        short8 o;
        o[0] = (short)f2bf(lo.x); o[1] = (short)f2bf(lo.y);
        o[2] = (short)f2bf(lo.z); o[3] = (short)f2bf(lo.w);
        o[4] = (short)f2bf(hi.x); o[5] = (short)f2bf(hi.y);
        o[6] = (short)f2bf(hi.z); o[7] = (short)f2bf(hi.w);
        am[mt] = o;
      }
      if (ks < 14) {                            // refill ring with ks+2
#pragma unroll
        for (int mt = 0; mt < 2; ++mt) {
          const float* p = ax + (size_t)mt * 16 * DIM + (ks + 2) * 32;
          aN[ring][mt][0] = *(const float4*)p;
          aN[ring][mt][1] = *(const float4*)(p + 4);
        }
      }
      short8 bn[4];
#pragma unroll
      for (int nt = 0; nt < 4; ++nt) {
        int col = nt * 16 + c;
        bn[nt] = *(const short8*)((char*)Bs + col * 1024 + ((ks * 64 + g * 16) ^ ((c & 7) << 4)));
      }
#pragma unroll
      for (int mt = 0; mt < 2; ++mt)
#pragma unroll
        for (int nt = 0; nt < 4; ++nt)
          acc[mt][nt] = __builtin_amdgcn_mfma_f32_16x16x32_bf16(am[mt], bn[nt], acc[mt][nt], 0, 0, 0);
    }

    // epilogue (R10 pattern, refcheck-passed): rope pairs acc[.][0]<->[2], [1]<->[3]; LN via shfl c-bits
#pragma unroll
    for (int mt = 0; mt < 2; ++mt) {
#pragma unroll
      for (int r = 0; r < 4; ++r) {
        const int mi = m0w + mt * 16 + 4 * g + r;
        const int b = mi / NPOS, pos = mi % NPOS;
        float cc0 = ctab[pos * 32 + c],      ss0 = stab[pos * 32 + c];
        float cc1 = ctab[pos * 32 + 16 + c], ss1 = stab[pos * 32 + 16 + c];
        float v1a = acc[mt][0][r], v2a = acc[mt][2][r];
        float v1b = acc[mt][1][r], v2b = acc[mt][3][r];
        float o0 = v1a * cc0 - v2a * ss0;
        float o2 = v2a * cc0 + v1a * ss0;
        float o1 = v1b * cc1 - v2b * ss1;
        float o3 = v2b * cc1 + v1b * ss1;
        float sum = (o0 + o1) + (o2 + o3);
        sum += __shfl_xor(sum, 1); sum += __shfl_xor(sum, 2);
        sum += __shfl_xor(sum, 4); sum += __shfl_xor(sum, 8);
        float mu = sum * 0.015625f;
        float d0 = o0 - mu, d1 = o1 - mu, d2 = o2 - mu, d3 = o3 - mu;
        float sq = fmaf(d0, d0, fmaf(d1, d1, fmaf(d2, d2, d3 * d3)));
        sq += __shfl_xor(sq, 1); sq += __shfl_xor(sq, 2);
        sq += __shfl_xor(sq, 4); sq += __shfl_xor(sq, 8);
        float rstd = rsqrtf(sq * 0.015625f + 1e-5f);
        u16* kvp = kvws + ((size_t)(b * 8 + nh) * NPOS + pos) * DH;
        kvp[c]      = f2bf(o0);
        kvp[16 + c] = f2bf(o1);
        kvp[32 + c] = f2bf(o2);
        kvp[48 + c] = f2bf(o3);
        if (c == 0) stats[(size_t)(b * 8 + nh) * NPOS + pos] = make_float2(mu, rstd);
      }
    }
  }
}

// ---------------- kernel 3: flash attention, LN folded out of PV (4 chunks, validated) ----------------
// out_d = (g_d*(O_d - Q2) + b_d*L)/L with O = sum p*rstd*kv, Q2 = sum p*mu*rstd, L = sum p.
__global__ __launch_bounds__(256) void k_attn(
    const u16* __restrict__ qws, const u16* __restrict__ kvws,
    const float2* __restrict__ stats,
    float* __restrict__ pout, float* __restrict__ pml) {
  __shared__ __align__(16) u16 LT[64 * 64];        // raw kv^T [dd][j], rows XOR-swizzled
  __shared__ __align__(16) u16 Pl[4][16 * 64];     // per-wave P' [i][j], XOR-swizzled
  int t = threadIdx.x;
  int lane = t & 63, w = t >> 6;
  int c = lane & 15, g = lane >> 4;
  int bh = blockIdx.y, chunk = blockIdx.x;
  int tt0 = chunk * TPC;
  int tt1 = tt0 + TPC; if (tt1 > NTILES) tt1 = NTILES;
  short8 qa[2];
  {
    const u16* qrow = qws + ((size_t)bh * LAT + w * 16 + c) * DH;
    qa[0] = *(const short8*)(qrow + 8 * g);
    qa[1] = *(const short8*)(qrow + 32 + 8 * g);
  }
  f32x4 oacc[4];
#pragma unroll
  for (int nt = 0; nt < 4; ++nt) oacc[nt] = (f32x4){0.f, 0.f, 0.f, 0.f};
  float m_run[4], l_run[4], q2_run[4];
#pragma unroll
  for (int r = 0; r < 4; ++r) { m_run[r] = -INFINITY; l_run[r] = 0.f; q2_run[r] = 0.f; }
  int sj = t & 63, sw = t >> 6;
  for (int tt = tt0; tt < tt1; ++tt) {
    int j0 = tt * 64;
    __syncthreads();
    {                                               // pure transpose staging: LT[dd][j] = kv[j][dd]
      const u16* src = kvws + ((size_t)bh * NPOS + j0 + sj) * DH + 16 * sw;
      short8 v0 = *(const short8*)src;
      short8 v1 = *(const short8*)(src + 8);
      char* ltb = (char*)LT;
#pragma unroll
      for (int e = 0; e < 16; ++e) {
        int dd = 16 * sw + e;
        u16 uv = (u16)((e < 8) ? v0[e] : v1[e - 8]);
        *(u16*)(ltb + dd * 128 + ((2 * sj) ^ ((dd & 7) << 4))) = uv;
      }
    }
    __syncthreads();
    f32x4 sacc[4];
#pragma unroll
    for (int jn = 0; jn < 4; ++jn) sacc[jn] = (f32x4){0.f, 0.f, 0.f, 0.f};
    const u16* kb = kvws + ((size_t)bh * NPOS + j0) * DH;
#pragma unroll
    for (int ks = 0; ks < 2; ++ks)
#pragma unroll
      for (int jn = 0; jn < 4; ++jn) {
        short8 kf = *(const short8*)(kb + (size_t)(jn * 16 + c) * DH + ks * 32 + 8 * g);
        sacc[jn] = __builtin_amdgcn_mfma_f32_16x16x32_bf16(qa[ks], kf, sacc[jn], 0, 0, 0);
      }
    float rsd[4], musig[4];
#pragma unroll
    for (int jn = 0; jn < 4; ++jn) {
      float2 sv = stats[(size_t)bh * NPOS + j0 + jn * 16 + c];
      rsd[jn] = sv.y; musig[jn] = sv.x * sv.y;
    }
    char* pb = (char*)Pl[w];
#pragma unroll
    for (int r = 0; r < 4; ++r) {
      float mt0 = fmaxf(fmaxf(sacc[0][r], sacc[1][r]), fmaxf(sacc[2][r], sacc[3][r]));
      mt0 = fmaxf(mt0, __shfl_xor(mt0, 1));
      mt0 = fmaxf(mt0, __shfl_xor(mt0, 2));
      mt0 = fmaxf(mt0, __shfl_xor(mt0, 4));
      mt0 = fmaxf(mt0, __shfl_xor(mt0, 8));
      float mnew = fmaxf(m_run[r], mt0);
      float corr = __expf(m_run[r] - mnew);
      m_run[r] = mnew;
      float ts = 0.f, tq = 0.f;
#pragma unroll
      for (int jn = 0; jn < 4; ++jn) {
        float p = __expf(sacc[jn][r] - mnew);
        ts += p;
        tq = fmaf(p, musig[jn], tq);
        sacc[jn][r] = p * rsd[jn];              // P' = p * rstd_j
      }
      ts += __shfl_xor(ts, 1); ts += __shfl_xor(ts, 2);
      ts += __shfl_xor(ts, 4); ts += __shfl_xor(ts, 8);
      tq += __shfl_xor(tq, 1); tq += __shfl_xor(tq, 2);
      tq += __shfl_xor(tq, 4); tq += __shfl_xor(tq, 8);
      l_run[r]  = l_run[r]  * corr + ts;
      q2_run[r] = q2_run[r] * corr + tq;
#pragma unroll
      for (int nt = 0; nt < 4; ++nt) oacc[nt][r] *= corr;
      int i = 4 * g + r;
      int isw = (i & 7) << 4;
#pragma unroll
      for (int jn = 0; jn < 4; ++jn) {
        int j = jn * 16 + c;
        *(u16*)(pb + i * 128 + ((2 * j) ^ isw)) = f2bf(sacc[jn][r]);
      }
    }
#pragma unroll
    for (int ks = 0; ks < 2; ++ks) {
      short8 pa = *(const short8*)(pb + c * 128 + ((ks * 64 + 16 * g) ^ ((c & 7) << 4)));
#pragma unroll
      for (int nt = 0; nt < 4; ++nt) {
        int dd = nt * 16 + c;
        short8 lv = *(const short8*)((char*)LT + dd * 128 + ((ks * 64 + 16 * g) ^ ((dd & 7) << 4)));
        oacc[nt] = __builtin_amdgcn_mfma_f32_16x16x32_bf16(pa, lv, oacc[nt], 0, 0, 0);
      }
    }
  }
  size_t ob = (size_t)bh * NCHUNK + chunk;
#pragma unroll
  for (int nt = 0; nt < 4; ++nt)
#pragma unroll
    for (int r = 0; r < 4; ++r) {
      int i = w * 16 + 4 * g + r;
      pout[(ob * 64 + i) * 64 + nt * 16 + c] = oacc[nt][r];
    }
  if (c == 0) {
#pragma unroll
    for (int r = 0; r < 4; ++r) {
      int i = w * 16 + 4 * g + r;
      pml[(ob * 3 + 0) * 64 + i] = m_run[r];
      pml[(ob * 3 + 1) * 64 + i] = l_run[r];
      pml[(ob * 3 + 2) * 64 + i] = q2_run[r];
    }
  }
}

// ---------------- kernel 4: combine chunks, apply LN gamma/beta, permute to output ----------------
__global__ __launch_bounds__(256) void k_combine(
    const float* __restrict__ pout, const float* __restrict__ pml,
    const float* __restrict__ lng, const float* __restrict__ lnb,
    float* __restrict__ out) {
  int bh = blockIdx.x, t = threadIdx.x;
  int i = t >> 2, dq = t & 3;
  float mv[NCHUNK], lv[NCHUNK], qv[NCHUNK];
#pragma unroll
  for (int cc = 0; cc < NCHUNK; ++cc) {
    size_t ob = (size_t)bh * NCHUNK + cc;
    mv[cc] = pml[(ob * 3 + 0) * 64 + i];
    lv[cc] = pml[(ob * 3 + 1) * 64 + i];
    qv[cc] = pml[(ob * 3 + 2) * 64 + i];
  }
  float M = -INFINITY;
#pragma unroll
  for (int cc = 0; cc < NCHUNK; ++cc) M = fmaxf(M, mv[cc]);
  float L = 0.f, Q2 = 0.f, wcf[NCHUNK];
#pragma unroll
  for (int cc = 0; cc < NCHUNK; ++cc) {
    wcf[cc] = __expf(mv[cc] - M);
    L = fmaf(wcf[cc], lv[cc], L);
    Q2 = fmaf(wcf[cc], qv[cc], Q2);
  }
  float invL = 1.0f / L;
#pragma unroll
  for (int e = 0; e < 16; ++e) {
    int dd = dq * 16 + e;
    float O = 0.f;
#pragma unroll
    for (int cc = 0; cc < NCHUNK; ++cc)
      O = fmaf(wcf[cc], pout[(((size_t)bh * NCHUNK + cc) * 64 + i) * 64 + dd], O);
    float val = (lng[dd] * (O - Q2) + lnb[dd] * L) * invL;
    out[((size_t)(bh >> 3) * LAT + i) * DIM + (bh & 7) * DH + dd] = val;
  }
}

extern "C" void kernel_launch(void* const* d_in, const int* in_sizes, int n_in,
                              void* d_out, int out_size, void* d_ws, size_t ws_size,
                              hipStream_t stream) {
  const float* x   = (const float*)d_in[0];
  const float* wq  = (const float*)d_in[1];
  const float* wkv = (const float*)d_in[2];
  const float* lng = (const float*)d_in[3];
  const float* lnb = (const float*)d_in[4];
  float* out = (float*)d_out;
  char* ws = (char*)d_ws;
  size_t off = 0;
  auto alloc = [&](size_t bytes) { char* p = ws + off; off += (bytes + 255) & ~(size_t)255; return p; };
  float*  ctab  = (float*)alloc((size_t)NPOS * 32 * 4);
  float*  stab  = (float*)alloc((size_t)NPOS * 32 * 4);
  u16*    qws   = (u16*)alloc((size_t)NBH * LAT * DH * 2);
  u16*    kvws  = (u16*)alloc((size_t)NBH * NPOS * DH * 2);
  float2* stats = (float2*)alloc((size_t)NBH * NPOS * 8);
  float*  pout  = (float*)alloc((size_t)NBH * NCHUNK * 64 * 64 * 4);
  float*  pml   = (float*)alloc((size_t)NBH * NCHUNK * 3 * 64 * 4);
  u16*    wbf   = (u16*)alloc((size_t)DIM * DIM * 2);
  (void)in_sizes; (void)n_in; (void)out_size; (void)ws_size;

  hipLaunchKernelGGL(k_rtable, dim3(NPOS * 32 / 256), dim3(256), 0, stream, ctab, stab);
  hipLaunchKernelGGL(k_wcast, dim3(DIM * DIM / 8 / 256), dim3(256), 0, stream, wkv, wbf);
  hipLaunchKernelGGL(k_qproj, dim3(128), dim3(256), 0, stream, x, wq, ctab, stab, qws);
  hipLaunchKernelGGL(k_kvgemm, dim3(1032), dim3(512), 0, stream, x, wbf, ctab, stab, kvws, stats);
  hipLaunchKernelGGL(k_attn, dim3(NCHUNK, NBH), dim3(256), 0, stream, qws, kvws, stats, pout, pml);
  hipLaunchKernelGGL(k_combine, dim3(NBH), dim3(256), 0, stream, pout, pml, lng, lnb, out);
}

// Round 14
// 400.011 us; speedup vs baseline: 2.4457x; 2.4457x over previous
//
#include <hip/hip_runtime.h>
#include <hip/hip_bf16.h>
#include <math.h>

#define SEQ_LEN 8192
#define LAT 64
#define NPOS 8256          // SEQ_LEN + LAT
#define NBATCH 16
#define NHEADS 8
#define DH 64
#define DIM 512
#define NBH 128            // NBATCH*NHEADS
#define NROWS 132096       // NBATCH*NPOS = 1032*128
#define NCHUNK 4
#define NTILES 129         // NPOS/64
#define TPC 33             // tiles per chunk (4*33=132 >= 129)

typedef unsigned short u16;
typedef unsigned int   u32;
using short8 = __attribute__((ext_vector_type(8))) short;  // MFMA bf16 A/B frag
using f32x4  = __attribute__((ext_vector_type(4))) float;  // MFMA C/D frag

static __device__ __forceinline__ float bf2f(u16 u) {
  union { u32 i; float f; } v; v.i = ((u32)u) << 16; return v.f;
}
static __device__ __forceinline__ u16 f2bf(float f) {  // round-to-nearest-even (manual, known-good)
  union { float f; u32 i; } v; v.f = f;
  u32 x = v.i;
  return (u16)((x + 0x7fffu + ((x >> 16) & 1u)) >> 16);
}
static __device__ __forceinline__ void gload_lds16(const void* g, void* l) {
  __builtin_amdgcn_global_load_lds(
      (const __attribute__((address_space(1))) unsigned int*)g,
      (__attribute__((address_space(3))) unsigned int*)l, 16, 0, 0);
}

// ---------------- kernel 0: rope tables ----------------
__global__ void k_rtable(float* __restrict__ ctab, float* __restrict__ stab) {
  int idx = blockIdx.x * 256 + threadIdx.x;   // NPOS*32 total
  int pos = idx >> 5, i = idx & 31;
  float inv = (float)(1.0 / pow(10000.0, (double)(2 * i) / 64.0));
  float ang = (float)pos * inv;
  ctab[idx] = cosf(ang);
  stab[idx] = sinf(ang);
}

// ---------------- kernel 0b: cast wkv to bf16 ----------------
__global__ __launch_bounds__(256) void k_wcast(const float* __restrict__ wkv, u16* __restrict__ wbf) {
  size_t i = (size_t)blockIdx.x * 256 + threadIdx.x;   // DIM*DIM/8 iters
  const float4* src = (const float4*)wkv;
  float4 a = src[2 * i], b = src[2 * i + 1];
  uint4 o;
  o.x = (u32)f2bf(a.x) | ((u32)f2bf(a.y) << 16);
  o.y = (u32)f2bf(a.z) | ((u32)f2bf(a.w) << 16);
  o.z = (u32)f2bf(b.x) | ((u32)f2bf(b.y) << 16);
  o.w = (u32)f2bf(b.z) | ((u32)f2bf(b.w) << 16);
  ((uint4*)wbf)[i] = o;
}

// ---------------- kernel 1: q projection (latent rows only) + rope + scale ----------------
__global__ __launch_bounds__(256) void k_qproj(
    const float* __restrict__ x, const float* __restrict__ wq,
    const float* __restrict__ ctab, const float* __restrict__ stab,
    u16* __restrict__ qws) {
  __shared__ __align__(16) float xs[8 * 512];
  int t = threadIdx.x;
  int lr0 = blockIdx.x * 8;
  int batch = lr0 >> 6;
  int lat0 = lr0 & 63;
  for (int u = 0; u < 4; ++u) {
    int e = u * 256 + t;
    int row = e >> 7, c4 = e & 127;
    size_t m = (size_t)batch * NPOS + SEQ_LEN + lat0 + row;
    ((float4*)xs)[e] = ((const float4*)(x + m * DIM))[c4];
  }
  __syncthreads();
  float acc0[8], acc1[8];
#pragma unroll
  for (int r = 0; r < 8; ++r) { acc0[r] = 0.f; acc1[r] = 0.f; }
  const float4* w0 = (const float4*)(wq + (size_t)t * DIM);
  const float4* w1 = (const float4*)(wq + (size_t)(t + 256) * DIM);
  for (int kk = 0; kk < 128; ++kk) {
    float4 a = w0[kk], b = w1[kk];
#pragma unroll
    for (int r = 0; r < 8; ++r) {
      float4 xv = ((const float4*)xs)[r * 128 + kk];
      acc0[r] = fmaf(a.x, xv.x, fmaf(a.y, xv.y, fmaf(a.z, xv.z, fmaf(a.w, xv.w, acc0[r]))));
      acc1[r] = fmaf(b.x, xv.x, fmaf(b.y, xv.y, fmaf(b.z, xv.z, fmaf(b.w, xv.w, acc1[r]))));
    }
  }
  __syncthreads();
#pragma unroll
  for (int r = 0; r < 8; ++r) { xs[r * 512 + t] = acc0[r]; xs[r * 512 + t + 256] = acc1[r]; }
  __syncthreads();
  int rh = t >> 2, sub = t & 3;
  int row = rh >> 3, head = rh & 7;
  int lat = lat0 + row, pos = SEQ_LEN + lat;
  int bh = batch * 8 + head;
  u16* qd = qws + ((size_t)bh * LAT + lat) * DH;
#pragma unroll
  for (int u = 0; u < 8; ++u) {
    int i = sub * 8 + u;
    float v1 = xs[row * 512 + head * 64 + i];
    float v2 = xs[row * 512 + head * 64 + i + 32];
    float cc = ctab[pos * 32 + i], ss = stab[pos * 32 + i];
    qd[i]      = f2bf((v1 * cc - v2 * ss) * 0.125f);
    qd[i + 32] = f2bf((v2 * cc + v1 * ss) * 0.125f);
  }
}

// ---------------- kernel 2: kv = x @ wbf^T, fused f32->bf16 A-staging, dbuf (R4, known-good) ----------------
__global__ __launch_bounds__(256, 2) void k_kvgemm(
    const float* __restrict__ x, const u16* __restrict__ wbf,
    const float* __restrict__ ctab, const float* __restrict__ stab,
    u16* __restrict__ kvws, float2* __restrict__ stats) {
  __shared__ __align__(16) char smem[65536];   // A0|A1|B0|B1 16KB each; reused as Cs[64][132] f32
  float* Cs = (float*)smem;
  int t = threadIdx.x;
  int lane = t & 63, w = t >> 6;
  int wr = w >> 1, wc = w & 1;
  int c = lane & 15, g = lane >> 4;
  // bijective XCD swizzle: 4128 = 8 * 516; n fastest within m-panel
  int s = (blockIdx.x & 7) * 516 + (blockIdx.x >> 3);
  int n0 = (s & 3) * 128;
  size_t m0 = (size_t)(s >> 2) * 128;

  f32x4 acc[4][4];
#pragma unroll
  for (int mt = 0; mt < 4; ++mt)
#pragma unroll
    for (int nt = 0; nt < 4; ++nt) acc[mt][nt] = (f32x4){0.f, 0.f, 0.f, 0.f};

  int ar = t >> 3, ac8 = t & 7;
  const float* axbase = x + (m0 + ar) * DIM + ac8 * 8;
  int aswz = (ac8 * 16) ^ ((ar & 7) << 4);
  int tcs = ((t & 7) ^ (ar & 7)) << 4;
  const char* bgsrc = (const char*)(wbf + (size_t)(n0 + ar) * DIM) + tcs;

  float4 a0[4], a1[4];
  auto issueA = [&](int kt) {
#pragma unroll
    for (int u = 0; u < 4; ++u) {
      const float* p = axbase + (size_t)u * 32 * DIM + kt * 64;
      a0[u] = *(const float4*)p;
      a1[u] = *(const float4*)(p + 4);
    }
  };
  auto issueB = [&](int kt, char* bbuf) {
    const char* bg = bgsrc + kt * 128;
    char* bl = bbuf + t * 16;
#pragma unroll
    for (int u = 0; u < 4; ++u) gload_lds16(bg + (size_t)u * 32 * 1024, bl + u * 4096);
  };
  auto writeA = [&](char* abuf) {
#pragma unroll
    for (int u = 0; u < 4; ++u) {
      short8 o;
      o[0] = (short)f2bf(a0[u].x); o[1] = (short)f2bf(a0[u].y);
      o[2] = (short)f2bf(a0[u].z); o[3] = (short)f2bf(a0[u].w);
      o[4] = (short)f2bf(a1[u].x); o[5] = (short)f2bf(a1[u].y);
      o[6] = (short)f2bf(a1[u].z); o[7] = (short)f2bf(a1[u].w);
      *(short8*)(abuf + (u * 32 + ar) * 128 + aswz) = o;
    }
  };

  issueA(0);
  issueB(0, smem + 32768);
  writeA(smem);
  __syncthreads();

#pragma unroll
  for (int kt = 0; kt < 8; ++kt) {
    char* Acur = smem + (kt & 1) * 16384;
    char* Bcur = smem + 32768 + (kt & 1) * 16384;
    char* Anxt = smem + ((kt & 1) ^ 1) * 16384;
    char* Bnxt = smem + 32768 + ((kt & 1) ^ 1) * 16384;
    if (kt < 7) { issueA(kt + 1); issueB(kt + 1, Bnxt); }
#pragma unroll
    for (int ks = 0; ks < 2; ++ks) {
      short8 am[4], bn[4];
#pragma unroll
      for (int mt = 0; mt < 4; ++mt) {
        int row = wr * 64 + mt * 16 + c;
        am[mt] = *(const short8*)(Acur + row * 128 + ((ks * 64 + g * 16) ^ ((row & 7) << 4)));
      }
#pragma unroll
      for (int nt = 0; nt < 4; ++nt) {
        int row = wc * 64 + nt * 16 + c;
        bn[nt] = *(const short8*)(Bcur + row * 128 + ((ks * 64 + g * 16) ^ ((row & 7) << 4)));
      }
#pragma unroll
      for (int mt = 0; mt < 4; ++mt)
#pragma unroll
        for (int nt = 0; nt < 4; ++nt)
          acc[mt][nt] = __builtin_amdgcn_mfma_f32_16x16x32_bf16(am[mt], bn[nt], acc[mt][nt], 0, 0, 0);
    }
    if (kt < 7) writeA(Anxt);
    __syncthreads();
  }

  // two-pass epilogue: pass p handles rows [p*64, p*64+64) via Cs[64][132] f32
  for (int p = 0; p < 2; ++p) {
    __syncthreads();
    if (wr == p) {
#pragma unroll
      for (int mt = 0; mt < 4; ++mt)
#pragma unroll
        for (int nt = 0; nt < 4; ++nt)
#pragma unroll
          for (int r = 0; r < 4; ++r)
            Cs[(mt * 16 + 4 * g + r) * 132 + wc * 64 + nt * 16 + c] = acc[mt][nt][r];
    }
    __syncthreads();
    if (t < 128) {
      int r_ = t & 63, hh = t >> 6;
      float v[64];
      const float4* crow = (const float4*)(Cs + r_ * 132 + hh * 64);
#pragma unroll
      for (int q = 0; q < 16; ++q) {
        float4 f = crow[q];
        v[4 * q] = f.x; v[4 * q + 1] = f.y; v[4 * q + 2] = f.z; v[4 * q + 3] = f.w;
      }
      int mi = (int)(m0 + p * 64 + r_);
      int b = mi / NPOS, pos = mi % NPOS;
      const float* ct = ctab + pos * 32;
      const float* st = stab + pos * 32;
#pragma unroll
      for (int i = 0; i < 32; ++i) {
        float cc = ct[i], ss = st[i];
        float v1 = v[i], v2 = v[i + 32];
        v[i]      = v1 * cc - v2 * ss;
        v[i + 32] = v2 * cc + v1 * ss;
      }
      float sum = 0.f;
#pragma unroll
      for (int e = 0; e < 64; ++e) sum += v[e];
      float mu = sum * 0.015625f;
      float sq = 0.f;
#pragma unroll
      for (int e = 0; e < 64; ++e) { float d = v[e] - mu; sq = fmaf(d, d, sq); }
      float rstd = rsqrtf(sq * 0.015625f + 1e-5f);
      int head = (n0 >> 6) + hh;
      int bh = b * 8 + head;
      u32 pk[32];
#pragma unroll
      for (int e = 0; e < 32; ++e) pk[e] = (u32)f2bf(v[2 * e]) | ((u32)f2bf(v[2 * e + 1]) << 16);
      uint4* dst = (uint4*)(kvws + ((size_t)bh * NPOS + pos) * DH);
#pragma unroll
      for (int u = 0; u < 8; ++u) dst[u] = make_uint4(pk[4 * u], pk[4 * u + 1], pk[4 * u + 2], pk[4 * u + 3]);
      stats[(size_t)bh * NPOS + pos] = make_float2(mu, rstd);
    }
  }
}

// ---------------- kernel 3: flash attention, LN folded out of PV (4 chunks, validated R10) ----------------
// out_d = (g_d*(O_d - Q2) + b_d*L)/L with O = sum p*rstd*kv, Q2 = sum p*mu*rstd, L = sum p.
__global__ __launch_bounds__(256) void k_attn(
    const u16* __restrict__ qws, const u16* __restrict__ kvws,
    const float2* __restrict__ stats,
    float* __restrict__ pout, float* __restrict__ pml) {
  __shared__ __align__(16) u16 LT[64 * 64];        // raw kv^T [dd][j], rows XOR-swizzled
  __shared__ __align__(16) u16 Pl[4][16 * 64];     // per-wave P' [i][j], XOR-swizzled
  int t = threadIdx.x;
  int lane = t & 63, w = t >> 6;
  int c = lane & 15, g = lane >> 4;
  int bh = blockIdx.y, chunk = blockIdx.x;
  int tt0 = chunk * TPC;
  int tt1 = tt0 + TPC; if (tt1 > NTILES) tt1 = NTILES;
  short8 qa[2];
  {
    const u16* qrow = qws + ((size_t)bh * LAT + w * 16 + c) * DH;
    qa[0] = *(const short8*)(qrow + 8 * g);
    qa[1] = *(const short8*)(qrow + 32 + 8 * g);
  }
  f32x4 oacc[4];
#pragma unroll
  for (int nt = 0; nt < 4; ++nt) oacc[nt] = (f32x4){0.f, 0.f, 0.f, 0.f};
  float m_run[4], l_run[4], q2_run[4];
#pragma unroll
  for (int r = 0; r < 4; ++r) { m_run[r] = -INFINITY; l_run[r] = 0.f; q2_run[r] = 0.f; }
  int sj = t & 63, sw = t >> 6;
  for (int tt = tt0; tt < tt1; ++tt) {
    int j0 = tt * 64;
    __syncthreads();
    {                                               // pure transpose staging: LT[dd][j] = kv[j][dd]
      const u16* src = kvws + ((size_t)bh * NPOS + j0 + sj) * DH + 16 * sw;
      short8 v0 = *(const short8*)src;
      short8 v1 = *(const short8*)(src + 8);
      char* ltb = (char*)LT;
#pragma unroll
      for (int e = 0; e < 16; ++e) {
        int dd = 16 * sw + e;
        u16 uv = (u16)((e < 8) ? v0[e] : v1[e - 8]);
        *(u16*)(ltb + dd * 128 + ((2 * sj) ^ ((dd & 7) << 4))) = uv;
      }
    }
    __syncthreads();
    f32x4 sacc[4];
#pragma unroll
    for (int jn = 0; jn < 4; ++jn) sacc[jn] = (f32x4){0.f, 0.f, 0.f, 0.f};
    const u16* kb = kvws + ((size_t)bh * NPOS + j0) * DH;
#pragma unroll
    for (int ks = 0; ks < 2; ++ks)
#pragma unroll
      for (int jn = 0; jn < 4; ++jn) {
        short8 kf = *(const short8*)(kb + (size_t)(jn * 16 + c) * DH + ks * 32 + 8 * g);
        sacc[jn] = __builtin_amdgcn_mfma_f32_16x16x32_bf16(qa[ks], kf, sacc[jn], 0, 0, 0);
      }
    float rsd[4], musig[4];
#pragma unroll
    for (int jn = 0; jn < 4; ++jn) {
      float2 sv = stats[(size_t)bh * NPOS + j0 + jn * 16 + c];
      rsd[jn] = sv.y; musig[jn] = sv.x * sv.y;
    }
    char* pb = (char*)Pl[w];
#pragma unroll
    for (int r = 0; r < 4; ++r) {
      float mt0 = fmaxf(fmaxf(sacc[0][r], sacc[1][r]), fmaxf(sacc[2][r], sacc[3][r]));
      mt0 = fmaxf(mt0, __shfl_xor(mt0, 1));
      mt0 = fmaxf(mt0, __shfl_xor(mt0, 2));
      mt0 = fmaxf(mt0, __shfl_xor(mt0, 4));
      mt0 = fmaxf(mt0, __shfl_xor(mt0, 8));
      float mnew = fmaxf(m_run[r], mt0);
      float corr = __expf(m_run[r] - mnew);
      m_run[r] = mnew;
      float ts = 0.f, tq = 0.f;
#pragma unroll
      for (int jn = 0; jn < 4; ++jn) {
        float p = __expf(sacc[jn][r] - mnew);
        ts += p;
        tq = fmaf(p, musig[jn], tq);
        sacc[jn][r] = p * rsd[jn];              // P' = p * rstd_j
      }
      ts += __shfl_xor(ts, 1); ts += __shfl_xor(ts, 2);
      ts += __shfl_xor(ts, 4); ts += __shfl_xor(ts, 8);
      tq += __shfl_xor(tq, 1); tq += __shfl_xor(tq, 2);
      tq += __shfl_xor(tq, 4); tq += __shfl_xor(tq, 8);
      l_run[r]  = l_run[r]  * corr + ts;
      q2_run[r] = q2_run[r] * corr + tq;
#pragma unroll
      for (int nt = 0; nt < 4; ++nt) oacc[nt][r] *= corr;
      int i = 4 * g + r;
      int isw = (i & 7) << 4;
#pragma unroll
      for (int jn = 0; jn < 4; ++jn) {
        int j = jn * 16 + c;
        *(u16*)(pb + i * 128 + ((2 * j) ^ isw)) = f2bf(sacc[jn][r]);
      }
    }
#pragma unroll
    for (int ks = 0; ks < 2; ++ks) {
      short8 pa = *(const short8*)(pb + c * 128 + ((ks * 64 + 16 * g) ^ ((c & 7) << 4)));
#pragma unroll
      for (int nt = 0; nt < 4; ++nt) {
        int dd = nt * 16 + c;
        short8 lv = *(const short8*)((char*)LT + dd * 128 + ((ks * 64 + 16 * g) ^ ((dd & 7) << 4)));
        oacc[nt] = __builtin_amdgcn_mfma_f32_16x16x32_bf16(pa, lv, oacc[nt], 0, 0, 0);
      }
    }
  }
  size_t ob = (size_t)bh * NCHUNK + chunk;
#pragma unroll
  for (int nt = 0; nt < 4; ++nt)
#pragma unroll
    for (int r = 0; r < 4; ++r) {
      int i = w * 16 + 4 * g + r;
      pout[(ob * 64 + i) * 64 + nt * 16 + c] = oacc[nt][r];
    }
  if (c == 0) {
#pragma unroll
    for (int r = 0; r < 4; ++r) {
      int i = w * 16 + 4 * g + r;
      pml[(ob * 3 + 0) * 64 + i] = m_run[r];
      pml[(ob * 3 + 1) * 64 + i] = l_run[r];
      pml[(ob * 3 + 2) * 64 + i] = q2_run[r];
    }
  }
}

// ---------------- kernel 4: combine chunks, apply LN gamma/beta, permute to output ----------------
__global__ __launch_bounds__(256) void k_combine(
    const float* __restrict__ pout, const float* __restrict__ pml,
    const float* __restrict__ lng, const float* __restrict__ lnb,
    float* __restrict__ out) {
  int bh = blockIdx.x, t = threadIdx.x;
  int i = t >> 2, dq = t & 3;
  float mv[NCHUNK], lv[NCHUNK], qv[NCHUNK];
#pragma unroll
  for (int cc = 0; cc < NCHUNK; ++cc) {
    size_t ob = (size_t)bh * NCHUNK + cc;
    mv[cc] = pml[(ob * 3 + 0) * 64 + i];
    lv[cc] = pml[(ob * 3 + 1) * 64 + i];
    qv[cc] = pml[(ob * 3 + 2) * 64 + i];
  }
  float M = -INFINITY;
#pragma unroll
  for (int cc = 0; cc < NCHUNK; ++cc) M = fmaxf(M, mv[cc]);
  float L = 0.f, Q2 = 0.f, wcf[NCHUNK];
#pragma unroll
  for (int cc = 0; cc < NCHUNK; ++cc) {
    wcf[cc] = __expf(mv[cc] - M);
    L = fmaf(wcf[cc], lv[cc], L);
    Q2 = fmaf(wcf[cc], qv[cc], Q2);
  }
  float invL = 1.0f / L;
#pragma unroll
  for (int e = 0; e < 16; ++e) {
    int dd = dq * 16 + e;
    float O = 0.f;
#pragma unroll
    for (int cc = 0; cc < NCHUNK; ++cc)
      O = fmaf(wcf[cc], pout[(((size_t)bh * NCHUNK + cc) * 64 + i) * 64 + dd], O);
    float val = (lng[dd] * (O - Q2) + lnb[dd] * L) * invL;
    out[((size_t)(bh >> 3) * LAT + i) * DIM + (bh & 7) * DH + dd] = val;
  }
}

extern "C" void kernel_launch(void* const* d_in, const int* in_sizes, int n_in,
                              void* d_out, int out_size, void* d_ws, size_t ws_size,
                              hipStream_t stream) {
  const float* x   = (const float*)d_in[0];
  const float* wq  = (const float*)d_in[1];
  const float* wkv = (const float*)d_in[2];
  const float* lng = (const float*)d_in[3];
  const float* lnb = (const float*)d_in[4];
  float* out = (float*)d_out;
  char* ws = (char*)d_ws;
  size_t off = 0;
  auto alloc = [&](size_t bytes) { char* p = ws + off; off += (bytes + 255) & ~(size_t)255; return p; };
  float*  ctab  = (float*)alloc((size_t)NPOS * 32 * 4);
  float*  stab  = (float*)alloc((size_t)NPOS * 32 * 4);
  u16*    qws   = (u16*)alloc((size_t)NBH * LAT * DH * 2);
  u16*    kvws  = (u16*)alloc((size_t)NBH * NPOS * DH * 2);
  float2* stats = (float2*)alloc((size_t)NBH * NPOS * 8);
  float*  pout  = (float*)alloc((size_t)NBH * NCHUNK * 64 * 64 * 4);
  float*  pml   = (float*)alloc((size_t)NBH * NCHUNK * 3 * 64 * 4);
  u16*    wbf   = (u16*)alloc((size_t)DIM * DIM * 2);
  (void)in_sizes; (void)n_in; (void)out_size; (void)ws_size;

  hipLaunchKernelGGL(k_rtable, dim3(NPOS * 32 / 256), dim3(256), 0, stream, ctab, stab);
  hipLaunchKernelGGL(k_wcast, dim3(DIM * DIM / 8 / 256), dim3(256), 0, stream, wkv, wbf);
  hipLaunchKernelGGL(k_qproj, dim3(128), dim3(256), 0, stream, x, wq, ctab, stab, qws);
  hipLaunchKernelGGL(k_kvgemm, dim3(4128), dim3(256), 0, stream, x, wbf, ctab, stab, kvws, stats);
  hipLaunchKernelGGL(k_attn, dim3(NCHUNK, NBH), dim3(256), 0, stream, qws, kvws, stats, pout, pml);
  hipLaunchKernelGGL(k_combine, dim3(NBH), dim3(256), 0, stream, pout, pml, lng, lnb, out);
}